// Round 2
// baseline (926.540 us; speedup 1.0000x reference)
//
#include <hip/hip_runtime.h>
#include <hip/hip_bf16.h>
#include <stdint.h>

typedef unsigned short ushortT;
typedef __bf16 bf16x8 __attribute__((ext_vector_type(8)));
typedef float f32x4 __attribute__((ext_vector_type(4)));
typedef unsigned short u16x8 __attribute__((ext_vector_type(8)));

#define N_TOK 131072
#define NSEG  256

__device__ __forceinline__ uint32_t f2bf(float f) {
  union { float f; uint32_t u; } c; c.f = f;
  uint32_t u = c.u;
  u += 0x7fffu + ((u >> 16) & 1u);   // RNE
  return u >> 16;
}
__device__ __forceinline__ float bf2f(uint32_t b) {
  union { uint32_t u; float f; } c; c.u = b << 16;
  return c.f;
}

__device__ __forceinline__ void gload_lds16(const void* g, void* l) {
  __builtin_amdgcn_global_load_lds(
      (const __attribute__((address_space(1))) void*)g,
      (__attribute__((address_space(3))) void*)l, 16, 0, 0);
}

// ---------------- prep kernels ----------------

__global__ void convert_bf16_kernel(const float* __restrict__ X, ushortT* __restrict__ Xb, int n4) {
  int i = blockIdx.x * 256 + threadIdx.x;
  const int stride = gridDim.x * 256;
  for (int idx = i; idx < n4; idx += stride) {
    const float4 v = ((const float4*)X)[idx];
    uint2 pk;
    pk.x = f2bf(v.x) | (f2bf(v.y) << 16);
    pk.y = f2bf(v.z) | (f2bf(v.w) << 16);
    ((uint2*)Xb)[idx] = pk;
  }
}

// WT[n*Kd + k] = bf16(W[k*Nd + n]);  W is [Kd][Nd] row-major
__global__ void transpose_bf16_kernel(const float* __restrict__ W, ushortT* __restrict__ WT,
                                      int Kd, int Nd) {
  int i = blockIdx.x * 256 + threadIdx.x;
  if (i < Kd * Nd) {
    int n = i / Kd, k = i % Kd;
    WT[i] = (ushortT)f2bf(W[(size_t)k * Nd + n]);
  }
}

// weff[c*8+h] = sum_d Wk[c,h*128+d]*Wq[h,d] / sqrt(128),  c in [0,640)
__global__ void weff_kernel(const float* __restrict__ Wk, const float* __restrict__ Wq,
                            float* __restrict__ weff) {
  const int c = blockIdx.x;       // 640
  const int lane = threadIdx.x;   // 64
  const float rs = 0.08838834764831845f;
#pragma unroll
  for (int h = 0; h < 8; ++h) {
    float acc = Wk[(size_t)c * 1024 + h * 128 + lane] * Wq[h * 128 + lane]
              + Wk[(size_t)c * 1024 + h * 128 + 64 + lane] * Wq[h * 128 + 64 + lane];
#pragma unroll
    for (int off = 32; off >= 1; off >>= 1) acc += __shfl_xor(acc, off, 64);
    if (lane == 0) weff[c * 8 + h] = acc * rs;
  }
}

// ---------------- GEMM: C[M,512] = relu?(A[M,K] @ W[K,512] + bias), BT = W^T [512][K] bf16 ----------------
// M given by grid: gridDim.x = (M/128)*4

template <int K, bool RELU, bool BIAS>
__global__ __launch_bounds__(256)
void gemm_bt_kernel(const ushortT* __restrict__ A, const ushortT* __restrict__ BT,
                    const float* __restrict__ bias, ushortT* __restrict__ C) {
  __shared__ ushortT lA[128 * 64];   // [row][k]
  __shared__ ushortT lB[128 * 64];   // [n][k]

  // XCD-aware swizzle (nwg always a multiple of 8 here: M multiple of 4096)
  const int nwg  = (int)gridDim.x;
  const int cpx  = nwg >> 3;
  const int flat = (int)blockIdx.x;
  const int swz  = (flat & 7) * cpx + (flat >> 3);
  const int bm   = swz >> 2;
  const int bn   = swz & 3;

  const int t = (int)threadIdx.x;
  const int w = t >> 6;
  const int lane = t & 63;
  const int wr = w >> 1, wc = w & 1;

  f32x4 acc[4][4];
#pragma unroll
  for (int i = 0; i < 4; ++i)
#pragma unroll
    for (int j = 0; j < 4; ++j) acc[i][j] = 0.f;

  const ushortT* Ab = A  + (size_t)bm * 128 * K;
  const ushortT* Bb = BT + (size_t)bn * 128 * K;
  const int r0 = w * 32 + (lane >> 3);  // + j*8
  const int c0 = (lane & 7) * 8;        // k element within BK tile
  char* lAc = (char*)lA + w * 4096;
  char* lBc = (char*)lB + w * 4096;

#pragma unroll 1
  for (int kt = 0; kt < K / 64; ++kt) {
    const int kofs = kt * 64 + c0;
#pragma unroll
    for (int j = 0; j < 4; ++j)
      gload_lds16(Ab + (size_t)(r0 + j * 8) * K + kofs, lAc + j * 1024);
#pragma unroll
    for (int j = 0; j < 4; ++j)
      gload_lds16(Bb + (size_t)(r0 + j * 8) * K + kofs, lBc + j * 1024);
    __syncthreads();

#pragma unroll
    for (int kk = 0; kk < 2; ++kk) {
      bf16x8 av[4], bv[4];
#pragma unroll
      for (int mi = 0; mi < 4; ++mi)
        av[mi] = *(const bf16x8*)&lA[(wr * 64 + mi * 16 + (lane & 15)) * 64 + kk * 32 + (lane >> 4) * 8];
#pragma unroll
      for (int ni = 0; ni < 4; ++ni)
        bv[ni] = *(const bf16x8*)&lB[(wc * 64 + ni * 16 + (lane & 15)) * 64 + kk * 32 + (lane >> 4) * 8];
#pragma unroll
      for (int mi = 0; mi < 4; ++mi)
#pragma unroll
        for (int ni = 0; ni < 4; ++ni)
          acc[mi][ni] = __builtin_amdgcn_mfma_f32_16x16x32_bf16(av[mi], bv[ni], acc[mi][ni], 0, 0, 0);
    }
    __syncthreads();
  }

  // C/D layout (m89-verified): col = lane&15, row = (lane>>4)*4 + reg
  const int row0 = bm * 128 + wr * 64 + (lane >> 4) * 4;
  const int col0 = bn * 128 + wc * 64 + (lane & 15);
#pragma unroll
  for (int ni = 0; ni < 4; ++ni) {
    const int col = col0 + ni * 16;
    const float bvv = BIAS ? bias[col] : 0.f;
#pragma unroll
    for (int mi = 0; mi < 4; ++mi) {
#pragma unroll
      for (int r = 0; r < 4; ++r) {
        float v = acc[mi][ni][r] + bvv;
        if (RELU) v = fmaxf(v, 0.f);
        C[(size_t)(row0 + mi * 16 + r) * 512 + col] = (ushortT)f2bf(v);
      }
    }
  }
}

// ---------------- segment prefix-mean scan with cross-chunk carry ----------------
// in-place on z: g = relu(cumsegmean(z) + br), chunk = global rows [c0, c0+rows)

__global__ __launch_bounds__(256)
void scan_kernel(ushortT* __restrict__ z, const int* __restrict__ seg,
                 const float* __restrict__ br, float* __restrict__ carry_sum,
                 int* __restrict__ carry_cnt, int c0, int rows) {
  const int s = (int)blockIdx.x;   // segment id
  const int t = (int)threadIdx.x;  // word (2 cols) owner

  int lo = c0, hi = c0 + rows;
  while (lo < hi) { int m = (lo + hi) >> 1; if (seg[m] < s) lo = m + 1; else hi = m; }
  const int beg = lo;
  hi = c0 + rows;
  while (lo < hi) { int m = (lo + hi) >> 1; if (seg[m] < s + 1) lo = m + 1; else hi = m; }
  const int end = lo;
  if (end <= beg) return;

  const float b0 = br[2 * t], b1v = br[2 * t + 1];
  float a0 = carry_sum[s * 512 + 2 * t];
  float a1 = carry_sum[s * 512 + 2 * t + 1];
  const int cntBase = carry_cnt[s];
  uint32_t* zp = (uint32_t*)z;

  constexpr int P = 16;   // prefetch depth (static-indexed ring)
  uint32_t buf[P];
#pragma unroll
  for (int p = 0; p < P; ++p)
    buf[p] = (beg + p < end) ? zp[(size_t)(beg + p - c0) * 256 + t] : 0u;

  for (int base = beg; base < end; base += P) {
#pragma unroll
    for (int p = 0; p < P; ++p) {
      const int r = base + p;
      if (r < end) {
        const uint32_t v = buf[p];
        buf[p] = (r + P < end) ? zp[(size_t)(r + P - c0) * 256 + t] : 0u;
        a0 += bf2f(v & 0xffffu);
        a1 += bf2f(v >> 16);
        const float inv = 1.0f / (float)(cntBase + r - beg + 1);
        const float g0 = fmaxf(fmaf(a0, inv, b0), 0.f);
        const float g1 = fmaxf(fmaf(a1, inv, b1v), 0.f);
        zp[(size_t)(r - c0) * 256 + t] = f2bf(g0) | (f2bf(g1) << 16);
      }
    }
  }

  carry_sum[s * 512 + 2 * t]     = a0;
  carry_sum[s * 512 + 2 * t + 1] = a1;
  if (t == 0) carry_cnt[s] = cntBase + (end - beg);
}

// ---------------- final: out[n,h] = X[n,:]@weff[0:128,h] + g[n,:]@weff[128:640,h] ----------------

__global__ __launch_bounds__(256)
void final_kernel(const float* __restrict__ X, const ushortT* __restrict__ g,
                  const float* __restrict__ weff, float* __restrict__ out, int rows) {
  const int t = (int)threadIdx.x;
  const int wv = t >> 6, lane = t & 63;

  float wx0[8], wx1[8], wg[8][8];
#pragma unroll
  for (int h = 0; h < 8; ++h) {
    wx0[h] = weff[(2 * lane) * 8 + h];
    wx1[h] = weff[(2 * lane + 1) * 8 + h];
  }
#pragma unroll
  for (int j = 0; j < 8; ++j)
#pragma unroll
    for (int h = 0; h < 8; ++h)
      wg[j][h] = weff[(128 + 8 * lane + j) * 8 + h];

  for (int row = (int)blockIdx.x * 4 + wv; row < rows; row += (int)gridDim.x * 4) {
    const float2 xv = *(const float2*)&X[(size_t)row * 128 + 2 * lane];
    const u16x8 gv = *(const u16x8*)&g[(size_t)row * 512 + 8 * lane];
    float pp[8];
#pragma unroll
    for (int h = 0; h < 8; ++h) pp[h] = xv.x * wx0[h] + xv.y * wx1[h];
#pragma unroll
    for (int j = 0; j < 8; ++j) {
      const float f = bf2f((uint32_t)gv[j]);
#pragma unroll
      for (int h = 0; h < 8; ++h) pp[h] = fmaf(f, wg[j][h], pp[h]);
    }
#pragma unroll
    for (int off = 32; off >= 1; off >>= 1) {
#pragma unroll
      for (int h = 0; h < 8; ++h) pp[h] += __shfl_xor(pp[h], off, 64);
    }
    if (lane == 0) {
#pragma unroll
      for (int h = 0; h < 8; ++h) out[(size_t)row * 8 + h] = pp[h];
    }
  }
}

// ---------------- launch ----------------

extern "C" void kernel_launch(void* const* d_in, const int* in_sizes, int n_in,
                              void* d_out, int out_size, void* d_ws, size_t ws_size,
                              hipStream_t stream) {
  const float* X  = (const float*)d_in[0];
  const int*   sg = (const int*)d_in[1];
  const float* W1 = (const float*)d_in[2];
  const float* b1 = (const float*)d_in[3];
  const float* W2 = (const float*)d_in[4];
  const float* b2 = (const float*)d_in[5];
  const float* W3 = (const float*)d_in[6];
  const float* b3 = (const float*)d_in[7];
  const float* Wr = (const float*)d_in[8];
  const float* br = (const float*)d_in[9];
  const float* Wk = (const float*)d_in[10];
  const float* Wq = (const float*)d_in[11];
  float* out = (float*)d_out;

  // fixed-size regions
  const size_t szW1T  = 512 * 128 * 2;
  const size_t szWT   = 512 * 512 * 2;
  const size_t szWeff = 640 * 8 * 4;
  const size_t szCSum = NSEG * 512 * 4;
  const size_t szCCnt = NSEG * 4;
  const size_t fixed  = szW1T + 3 * szWT + szWeff + szCSum + szCCnt;

  // pick the largest chunk (rows) whose buffers fit in ws
  int CH = 0;
  const int cands[6] = {131072, 65536, 32768, 16384, 8192, 4096};
  for (int i = 0; i < 6; ++i) {
    const size_t need = fixed + (size_t)cands[i] * 128 * 2     // Xb chunk
                      + 2 * (size_t)cands[i] * 512 * 2;        // ping-pong
    if (need <= ws_size) { CH = cands[i]; break; }
  }
  if (CH == 0) CH = 4096;  // attempt anyway

  char* p = (char*)d_ws;
  ushortT* W1T  = (ushortT*)p; p += szW1T;
  ushortT* W2T  = (ushortT*)p; p += szWT;
  ushortT* W3T  = (ushortT*)p; p += szWT;
  ushortT* WrT  = (ushortT*)p; p += szWT;
  float*   weff = (float*)p;   p += szWeff;
  float*   cSum = (float*)p;   p += szCSum;
  int*     cCnt = (int*)p;     p += szCCnt;
  ushortT* Xb   = (ushortT*)p; p += (size_t)CH * 128 * 2;
  ushortT* p1   = (ushortT*)p; p += (size_t)CH * 512 * 2;
  ushortT* p2   = (ushortT*)p;

  // prep (once)
  transpose_bf16_kernel<<<(512 * 128 + 255) / 256, 256, 0, stream>>>(W1, W1T, 128, 512);
  transpose_bf16_kernel<<<(512 * 512 + 255) / 256, 256, 0, stream>>>(W2, W2T, 512, 512);
  transpose_bf16_kernel<<<(512 * 512 + 255) / 256, 256, 0, stream>>>(W3, W3T, 512, 512);
  transpose_bf16_kernel<<<(512 * 512 + 255) / 256, 256, 0, stream>>>(Wr, WrT, 512, 512);
  weff_kernel<<<640, 64, 0, stream>>>(Wk, Wq, weff);
  hipMemsetAsync(cSum, 0, szCSum + szCCnt, stream);   // carry = 0

  for (int c0 = 0; c0 < N_TOK; c0 += CH) {
    const int gG = (CH / 128) * 4;
    const int gF = (CH / 4 < 4096) ? CH / 4 : 4096;
    convert_bf16_kernel<<<2048, 256, 0, stream>>>(X + (size_t)c0 * 128, Xb, CH * 128 / 4);
    gemm_bt_kernel<128, true,  true ><<<gG, 256, 0, stream>>>(Xb, W1T, b1, p1);
    gemm_bt_kernel<512, true,  true ><<<gG, 256, 0, stream>>>(p1, W2T, b2, p2);
    gemm_bt_kernel<512, true,  true ><<<gG, 256, 0, stream>>>(p2, W3T, b3, p1);
    gemm_bt_kernel<512, false, false><<<gG, 256, 0, stream>>>(p1, WrT, nullptr, p2);
    scan_kernel<<<NSEG, 256, 0, stream>>>(p2, sg, br, cSum, cCnt, c0, CH);
    final_kernel<<<gF, 256, 0, stream>>>(X + (size_t)c0 * 128, p2, weff,
                                         out + (size_t)c0 * 8, CH);
  }
}

// Round 3
// 643.385 us; speedup vs baseline: 1.4401x; 1.4401x over previous
//
#include <hip/hip_runtime.h>
#include <hip/hip_bf16.h>
#include <stdint.h>

typedef unsigned short ushortT;
typedef __bf16 bf16x8 __attribute__((ext_vector_type(8)));
typedef float f32x4 __attribute__((ext_vector_type(4)));
typedef unsigned short u16x8 __attribute__((ext_vector_type(8)));

#define N_TOK 131072
#define NSEG  256

__device__ __forceinline__ uint32_t f2bf(float f) {
  union { float f; uint32_t u; } c; c.f = f;
  uint32_t u = c.u;
  u += 0x7fffu + ((u >> 16) & 1u);   // RNE
  return u >> 16;
}
__device__ __forceinline__ float bf2f(uint32_t b) {
  union { uint32_t u; float f; } c; c.u = b << 16;
  return c.f;
}

__device__ __forceinline__ void gload_lds16(const void* g, void* l) {
  __builtin_amdgcn_global_load_lds(
      (const __attribute__((address_space(1))) void*)g,
      (__attribute__((address_space(3))) void*)l, 16, 0, 0);
}

// ---------------- prep kernels ----------------

__global__ void convert_bf16_kernel(const float* __restrict__ X, ushortT* __restrict__ Xb, int n4) {
  int i = blockIdx.x * 256 + threadIdx.x;
  const int stride = gridDim.x * 256;
  for (int idx = i; idx < n4; idx += stride) {
    const float4 v = ((const float4*)X)[idx];
    uint2 pk;
    pk.x = f2bf(v.x) | (f2bf(v.y) << 16);
    pk.y = f2bf(v.z) | (f2bf(v.w) << 16);
    ((uint2*)Xb)[idx] = pk;
  }
}

// WT[n*Kd + k] = bf16(W[k*Nd + n]);  W is [Kd][Nd] row-major
__global__ void transpose_bf16_kernel(const float* __restrict__ W, ushortT* __restrict__ WT,
                                      int Kd, int Nd) {
  int i = blockIdx.x * 256 + threadIdx.x;
  if (i < Kd * Nd) {
    int n = i / Kd, k = i % Kd;
    WT[i] = (ushortT)f2bf(W[(size_t)k * Nd + n]);
  }
}

// weff[c*8+h] = sum_d Wk[c,h*128+d]*Wq[h,d] / sqrt(128),  c in [0,640)
__global__ void weff_kernel(const float* __restrict__ Wk, const float* __restrict__ Wq,
                            float* __restrict__ weff) {
  const int c = blockIdx.x;       // 640
  const int lane = threadIdx.x;   // 64
  const float rs = 0.08838834764831845f;
#pragma unroll
  for (int h = 0; h < 8; ++h) {
    float acc = Wk[(size_t)c * 1024 + h * 128 + lane] * Wq[h * 128 + lane]
              + Wk[(size_t)c * 1024 + h * 128 + 64 + lane] * Wq[h * 128 + 64 + lane];
#pragma unroll
    for (int off = 32; off >= 1; off >>= 1) acc += __shfl_xor(acc, off, 64);
    if (lane == 0) weff[c * 8 + h] = acc * rs;
  }
}

// ---------------- GEMM: C[M,512] = relu?(A[M,K] @ W[K,512] + bias), BT = W^T [512][K] bf16 ----------------
// M given by grid: gridDim.x = (M/128)*4

template <int K, bool RELU, bool BIAS>
__global__ __launch_bounds__(256)
void gemm_bt_kernel(const ushortT* __restrict__ A, const ushortT* __restrict__ BT,
                    const float* __restrict__ bias, ushortT* __restrict__ C) {
  __shared__ ushortT lA[128 * 64];   // [row][k]
  __shared__ ushortT lB[128 * 64];   // [n][k]

  // XCD-aware swizzle (nwg always a multiple of 8 here: M multiple of 4096)
  const int nwg  = (int)gridDim.x;
  const int cpx  = nwg >> 3;
  const int flat = (int)blockIdx.x;
  const int swz  = (flat & 7) * cpx + (flat >> 3);
  const int bm   = swz >> 2;
  const int bn   = swz & 3;

  const int t = (int)threadIdx.x;
  const int w = t >> 6;
  const int lane = t & 63;
  const int wr = w >> 1, wc = w & 1;

  f32x4 acc[4][4];
#pragma unroll
  for (int i = 0; i < 4; ++i)
#pragma unroll
    for (int j = 0; j < 4; ++j) acc[i][j] = 0.f;

  const ushortT* Ab = A  + (size_t)bm * 128 * K;
  const ushortT* Bb = BT + (size_t)bn * 128 * K;
  const int r0 = w * 32 + (lane >> 3);  // + j*8
  const int c0 = (lane & 7) * 8;        // k element within BK tile
  char* lAc = (char*)lA + w * 4096;
  char* lBc = (char*)lB + w * 4096;

#pragma unroll 1
  for (int kt = 0; kt < K / 64; ++kt) {
    const int kofs = kt * 64 + c0;
#pragma unroll
    for (int j = 0; j < 4; ++j)
      gload_lds16(Ab + (size_t)(r0 + j * 8) * K + kofs, lAc + j * 1024);
#pragma unroll
    for (int j = 0; j < 4; ++j)
      gload_lds16(Bb + (size_t)(r0 + j * 8) * K + kofs, lBc + j * 1024);
    __syncthreads();

#pragma unroll
    for (int kk = 0; kk < 2; ++kk) {
      bf16x8 av[4], bv[4];
#pragma unroll
      for (int mi = 0; mi < 4; ++mi)
        av[mi] = *(const bf16x8*)&lA[(wr * 64 + mi * 16 + (lane & 15)) * 64 + kk * 32 + (lane >> 4) * 8];
#pragma unroll
      for (int ni = 0; ni < 4; ++ni)
        bv[ni] = *(const bf16x8*)&lB[(wc * 64 + ni * 16 + (lane & 15)) * 64 + kk * 32 + (lane >> 4) * 8];
#pragma unroll
      for (int mi = 0; mi < 4; ++mi)
#pragma unroll
        for (int ni = 0; ni < 4; ++ni)
          acc[mi][ni] = __builtin_amdgcn_mfma_f32_16x16x32_bf16(av[mi], bv[ni], acc[mi][ni], 0, 0, 0);
    }
    __syncthreads();
  }

  // C/D layout (m89-verified): col = lane&15, row = (lane>>4)*4 + reg
  const int row0 = bm * 128 + wr * 64 + (lane >> 4) * 4;
  const int col0 = bn * 128 + wc * 64 + (lane & 15);
#pragma unroll
  for (int ni = 0; ni < 4; ++ni) {
    const int col = col0 + ni * 16;
    const float bvv = BIAS ? bias[col] : 0.f;
#pragma unroll
    for (int mi = 0; mi < 4; ++mi) {
#pragma unroll
      for (int r = 0; r < 4; ++r) {
        float v = acc[mi][ni][r] + bvv;
        if (RELU) v = fmaxf(v, 0.f);
        C[(size_t)(row0 + mi * 16 + r) * 512 + col] = (ushortT)f2bf(v);
      }
    }
  }
}

// ---------------- segment prefix-mean scan with cross-chunk carry ----------------
// g = relu(cumsegmean(z) + br); z and g are DISJOINT buffers (restrict) so the
// prefetch ring pipelines. chunk = global rows [c0, c0+rows)

__global__ __launch_bounds__(256)
void scan_kernel(const ushortT* __restrict__ z, ushortT* __restrict__ gout,
                 const int* __restrict__ seg, const float* __restrict__ br,
                 float* __restrict__ carry_sum, int* __restrict__ carry_cnt,
                 int c0, int rows) {
  const int s = (int)blockIdx.x;   // segment id
  const int t = (int)threadIdx.x;  // word (2 cols) owner

  int lo = c0, hi = c0 + rows;
  while (lo < hi) { int m = (lo + hi) >> 1; if (seg[m] < s) lo = m + 1; else hi = m; }
  const int beg = lo;
  hi = c0 + rows;
  while (lo < hi) { int m = (lo + hi) >> 1; if (seg[m] < s + 1) lo = m + 1; else hi = m; }
  const int end = lo;
  if (end <= beg) return;

  const float b0 = br[2 * t], b1v = br[2 * t + 1];
  float a0 = carry_sum[s * 512 + 2 * t];
  float a1 = carry_sum[s * 512 + 2 * t + 1];
  const int cntBase = carry_cnt[s];
  const uint32_t* __restrict__ zp = (const uint32_t*)z;
  uint32_t* __restrict__ gp = (uint32_t*)gout;

  constexpr int P = 16;   // prefetch depth (static-indexed ring)
  uint32_t buf[P];
#pragma unroll
  for (int p = 0; p < P; ++p)
    buf[p] = (beg + p < end) ? zp[(size_t)(beg + p - c0) * 256 + t] : 0u;

  int base = beg;
  // steady state: no per-iteration guards -> loads stay 16 deep in flight
  for (; base + 2 * P <= end; base += P) {
#pragma unroll
    for (int p = 0; p < P; ++p) {
      const int r = base + p;
      const uint32_t v = buf[p];
      buf[p] = zp[(size_t)(r + P - c0) * 256 + t];
      a0 += bf2f(v & 0xffffu);
      a1 += bf2f(v >> 16);
      const float inv = 1.0f / (float)(cntBase + r - beg + 1);
      const float g0 = fmaxf(fmaf(a0, inv, b0), 0.f);
      const float g1 = fmaxf(fmaf(a1, inv, b1v), 0.f);
      gp[(size_t)(r - c0) * 256 + t] = f2bf(g0) | (f2bf(g1) << 16);
    }
  }
  // tail
  for (; base < end; base += P) {
#pragma unroll
    for (int p = 0; p < P; ++p) {
      const int r = base + p;
      if (r < end) {
        const uint32_t v = buf[p];
        buf[p] = (r + P < end) ? zp[(size_t)(r + P - c0) * 256 + t] : 0u;
        a0 += bf2f(v & 0xffffu);
        a1 += bf2f(v >> 16);
        const float inv = 1.0f / (float)(cntBase + r - beg + 1);
        const float g0 = fmaxf(fmaf(a0, inv, b0), 0.f);
        const float g1 = fmaxf(fmaf(a1, inv, b1v), 0.f);
        gp[(size_t)(r - c0) * 256 + t] = f2bf(g0) | (f2bf(g1) << 16);
      }
    }
  }

  carry_sum[s * 512 + 2 * t]     = a0;
  carry_sum[s * 512 + 2 * t + 1] = a1;
  if (t == 0) carry_cnt[s] = cntBase + (end - beg);
}

// ---------------- final: out[n,h] = X[n,:]@weff[0:128,h] + g[n,:]@weff[128:640,h] ----------------

__global__ __launch_bounds__(256)
void final_kernel(const float* __restrict__ X, const ushortT* __restrict__ g,
                  const float* __restrict__ weff, float* __restrict__ out, int rows) {
  const int t = (int)threadIdx.x;
  const int wv = t >> 6, lane = t & 63;

  float wx0[8], wx1[8], wg[8][8];
#pragma unroll
  for (int h = 0; h < 8; ++h) {
    wx0[h] = weff[(2 * lane) * 8 + h];
    wx1[h] = weff[(2 * lane + 1) * 8 + h];
  }
#pragma unroll
  for (int j = 0; j < 8; ++j)
#pragma unroll
    for (int h = 0; h < 8; ++h)
      wg[j][h] = weff[(128 + 8 * lane + j) * 8 + h];

  for (int row = (int)blockIdx.x * 4 + wv; row < rows; row += (int)gridDim.x * 4) {
    const float2 xv = *(const float2*)&X[(size_t)row * 128 + 2 * lane];
    const u16x8 gv = *(const u16x8*)&g[(size_t)row * 512 + 8 * lane];
    float pp[8];
#pragma unroll
    for (int h = 0; h < 8; ++h) pp[h] = xv.x * wx0[h] + xv.y * wx1[h];
#pragma unroll
    for (int j = 0; j < 8; ++j) {
      const float f = bf2f((uint32_t)gv[j]);
#pragma unroll
      for (int h = 0; h < 8; ++h) pp[h] = fmaf(f, wg[j][h], pp[h]);
    }
#pragma unroll
    for (int off = 32; off >= 1; off >>= 1) {
#pragma unroll
      for (int h = 0; h < 8; ++h) pp[h] += __shfl_xor(pp[h], off, 64);
    }
    if (lane == 0) {
#pragma unroll
      for (int h = 0; h < 8; ++h) out[(size_t)row * 8 + h] = pp[h];
    }
  }
}

// ---------------- launch ----------------

extern "C" void kernel_launch(void* const* d_in, const int* in_sizes, int n_in,
                              void* d_out, int out_size, void* d_ws, size_t ws_size,
                              hipStream_t stream) {
  const float* X  = (const float*)d_in[0];
  const int*   sg = (const int*)d_in[1];
  const float* W1 = (const float*)d_in[2];
  const float* b1 = (const float*)d_in[3];
  const float* W2 = (const float*)d_in[4];
  const float* b2 = (const float*)d_in[5];
  const float* W3 = (const float*)d_in[6];
  const float* b3 = (const float*)d_in[7];
  const float* Wr = (const float*)d_in[8];
  const float* br = (const float*)d_in[9];
  const float* Wk = (const float*)d_in[10];
  const float* Wq = (const float*)d_in[11];
  float* out = (float*)d_out;

  // fixed-size regions
  const size_t szW1T  = 512 * 128 * 2;
  const size_t szWT   = 512 * 512 * 2;
  const size_t szWeff = 640 * 8 * 4;
  const size_t szCSum = NSEG * 512 * 4;
  const size_t szCCnt = NSEG * 4;
  const size_t fixed  = szW1T + 3 * szWT + szWeff + szCSum + szCCnt;

  // pick the largest chunk (rows) whose buffers fit in ws
  int CH = 0;
  const int cands[6] = {131072, 65536, 32768, 16384, 8192, 4096};
  for (int i = 0; i < 6; ++i) {
    const size_t need = fixed + (size_t)cands[i] * 128 * 2     // Xb chunk
                      + 2 * (size_t)cands[i] * 512 * 2;        // ping-pong
    if (need <= ws_size) { CH = cands[i]; break; }
  }
  if (CH == 0) CH = 4096;  // attempt anyway

  char* p = (char*)d_ws;
  ushortT* W1T  = (ushortT*)p; p += szW1T;
  ushortT* W2T  = (ushortT*)p; p += szWT;
  ushortT* W3T  = (ushortT*)p; p += szWT;
  ushortT* WrT  = (ushortT*)p; p += szWT;
  float*   weff = (float*)p;   p += szWeff;
  float*   cSum = (float*)p;   p += szCSum;
  int*     cCnt = (int*)p;     p += szCCnt;
  ushortT* Xb   = (ushortT*)p; p += (size_t)CH * 128 * 2;
  ushortT* p1   = (ushortT*)p; p += (size_t)CH * 512 * 2;
  ushortT* p2   = (ushortT*)p;

  // prep (once)
  transpose_bf16_kernel<<<(512 * 128 + 255) / 256, 256, 0, stream>>>(W1, W1T, 128, 512);
  transpose_bf16_kernel<<<(512 * 512 + 255) / 256, 256, 0, stream>>>(W2, W2T, 512, 512);
  transpose_bf16_kernel<<<(512 * 512 + 255) / 256, 256, 0, stream>>>(W3, W3T, 512, 512);
  transpose_bf16_kernel<<<(512 * 512 + 255) / 256, 256, 0, stream>>>(Wr, WrT, 512, 512);
  weff_kernel<<<640, 64, 0, stream>>>(Wk, Wq, weff);
  hipMemsetAsync(cSum, 0, szCSum + szCCnt, stream);   // carry = 0

  for (int c0 = 0; c0 < N_TOK; c0 += CH) {
    const int gG = (CH / 128) * 4;
    const int gF = (CH / 4 < 4096) ? CH / 4 : 4096;
    convert_bf16_kernel<<<2048, 256, 0, stream>>>(X + (size_t)c0 * 128, Xb, CH * 128 / 4);
    gemm_bt_kernel<128, true,  true ><<<gG, 256, 0, stream>>>(Xb, W1T, b1, p1);
    gemm_bt_kernel<512, true,  true ><<<gG, 256, 0, stream>>>(p1, W2T, b2, p2);
    gemm_bt_kernel<512, true,  true ><<<gG, 256, 0, stream>>>(p2, W3T, b3, p1);
    gemm_bt_kernel<512, false, false><<<gG, 256, 0, stream>>>(p1, WrT, nullptr, p2);
    // scan reads p2 (z), writes p1 (enc is dead) -- disjoint buffers
    scan_kernel<<<NSEG, 256, 0, stream>>>(p2, p1, sg, br, cSum, cCnt, c0, CH);
    final_kernel<<<gF, 256, 0, stream>>>(X + (size_t)c0 * 128, p1, weff,
                                         out + (size_t)c0 * 8, CH);
  }
}